// Round 2
// baseline (1844.030 us; speedup 1.0000x reference)
//
#include <hip/hip_runtime.h>

typedef __attribute__((ext_vector_type(8))) __bf16 bf16x8;
typedef __attribute__((ext_vector_type(4))) float f32x4;

#define MFMA16(a, b, c) __builtin_amdgcn_mfma_f32_16x16x32_bf16(a, b, c, 0, 0, 0)

#define T_SEQ 512
#define F_IN 32
#define H1 128
#define E2 64
#define ROWS 4          // batch rows per block

__device__ __forceinline__ float bf2f(ushort u) {
    union { uint i; float f; } v; v.i = ((uint)u) << 16; return v.f;
}
__device__ __forceinline__ ushort f2bf(float f) {
    union { float f; uint i; } v; v.f = f;
    uint r = v.i + 0x7fffu + ((v.i >> 16) & 1u);
    return (ushort)(r >> 16);
}
__device__ __forceinline__ float fast_sigmoid(float x) {
    float e = __expf(-x);
    return __builtin_amdgcn_rcpf(1.0f + e);
}
__device__ __forceinline__ float fast_tanh(float x) {
    float e = __expf(-2.0f * x);
    return 2.0f * __builtin_amdgcn_rcpf(1.0f + e) - 1.0f;
}
__device__ __forceinline__ bf16x8 load_w8(const float* p) {
    bf16x8 r;
#pragma unroll
    for (int j = 0; j < 8; ++j) r[j] = (__bf16)p[j];
    return r;
}

// Fused 2-layer LSTM, 128 blocks x 256 threads (4 waves), 4 batch rows/block.
//
// ROUND THEORY (register-file cap): with 8 waves/block there are ALWAYS
// 2 waves/SIMD resident -> hard 256-reg/wave budget, and the allocator's
// rigid 128V+128A split spilled ~24-32 regs/thread no matter what
// launch-bounds said (WRITE_SIZE 7.5-8.5MB across rounds 0-1, VGPR stuck
// at 128). Fix: 4 waves = 1 wave/SIMD -> 512-reg budget. Each wave owns
// one full gate type for BOTH layers: 128 L1 cols (32 Whh1 + 8 Wih1
// frags) + 64 L2 cols (16 Wih2 + 8 Whh2 frags) = 256 weight regs,
// ~345 peak live. Also halves LDS A-frag redundancy (4 waves read the
// shared xs/h1s/h2s fragments instead of 8).
__global__ __launch_bounds__(256, 1) void lstm_fused(
    const float* __restrict__ x,      // [512][512][32]
    const float* __restrict__ Wih1,   // [512][32]
    const float* __restrict__ Whh1,   // [512][128]
    const float* __restrict__ bih1,   // [512]
    const float* __restrict__ bhh1,   // [512]
    const float* __restrict__ Wih2,   // [256][128]
    const float* __restrict__ Whh2,   // [256][64]
    const float* __restrict__ bih2,   // [256]
    const float* __restrict__ bhh2,   // [256]
    float* __restrict__ out)          // [512][64] fp32
{
    __shared__ ushort xs [16][72];    // x(t): cols 0..31 hi, 32..63 lo
    __shared__ ushort h1s[16][264];   // h1: cols 0..127 hi, 128..255 lo
    __shared__ ushort h2s[16][136];   // h2: cols 0..63 hi, 64..127 lo
    __shared__ float  g1r[ROWS][516]; // raw L1 gates (valid rows only)
    __shared__ float  g2r[ROWS][260]; // raw L2 gates

    const int tid  = threadIdx.x;
    const int wave = tid >> 6;        // 0..3 == gate type (i,f,g,o)
    const int lane = tid & 63;
    const int l15  = lane & 15;
    const int quad = lane >> 4;
    const int r0   = blockIdx.x * ROWS;

    // Weight fragment file (256 VGPRs of weights per wave):
    bf16x8 wh1[8][4];   // Whh1 rows wave*128+nt*16+l15, k-blk kt   (128 regs)
    bf16x8 wx1[8];      // Wih1 rows wave*128+nt*16+l15             (32 regs)
    bf16x8 wi2[4][4];   // Wih2 rows wave*64+mt*16+l15, k-blk kt    (64 regs)
    bf16x8 wh2[4][2];   // Whh2 rows wave*64+mt*16+l15, k-blk kt    (32 regs)
    float  b1[8], b2[4];

#pragma unroll
    for (int nt = 0; nt < 8; ++nt) {
        const int n = wave * 128 + nt * 16 + l15;
#pragma unroll
        for (int kt = 0; kt < 4; ++kt)
            wh1[nt][kt] = load_w8(Whh1 + n * H1 + kt * 32 + quad * 8);
        wx1[nt] = load_w8(Wih1 + n * F_IN + quad * 8);
        b1[nt] = bih1[n] + bhh1[n];
    }
#pragma unroll
    for (int mt = 0; mt < 4; ++mt) {
        const int n = wave * 64 + mt * 16 + l15;
#pragma unroll
        for (int kt = 0; kt < 4; ++kt)
            wi2[mt][kt] = load_w8(Wih2 + n * H1 + kt * 32 + quad * 8);
#pragma unroll
        for (int kt = 0; kt < 2; ++kt)
            wh2[mt][kt] = load_w8(Whh2 + n * E2 + kt * 32 + quad * 8);
        b2[mt] = bih2[n] + bhh2[n];
    }

    // zero h states (all 16 rows; rows >= ROWS stay zero forever)
    for (int i = tid; i < 16 * 264; i += 256) ((ushort*)h1s)[i] = 0;
    for (int i = tid; i < 16 * 136; i += 256) ((ushort*)h2s)[i] = 0;
    __syncthreads();

    // per-thread epilogue ownership + fp32 cell state
    // L1: 2 unit-rows per thread (idx = tid, tid+256); L2: 1 per thread
    const int e2row = tid >> 6, e2u = tid & 63;
    float c1[2] = {0.0f, 0.0f};
    float c2 = 0.0f;

    // x prefetch: threads 0..127 own (row = tid>>5, col = tid&31)
    const int xrow = tid >> 5, xcol = tid & 31;
    const float* xptr = x + ((size_t)(r0 + (xrow & 3)) * T_SEQ) * F_IN + xcol;
    float xreg = (tid < 128) ? xptr[0] : 0.0f;

#pragma unroll 1
    for (int tt = 0; tt <= T_SEQ; ++tt) {
        // ---- stage x(tt), prefetch x(tt+1) ----
        if (tt < T_SEQ && tid < 128) {
            const ushort h = f2bf(xreg);
            xs[xrow][xcol]      = h;
            xs[xrow][32 + xcol] = f2bf(xreg - bf2f(h));
            if (tt + 1 < T_SEQ) xreg = xptr[(tt + 1) * F_IN];
        }
        __syncthreads();   // B1: xs(tt), h1(tt-1), h2(tt-2) ready

        // ---- GEMM phase: every wave = one gate type, both layers ----
        const bool doL1 = (tt < T_SEQ);
        const bool doL2 = (tt >= 1);
        f32x4 acc1[8], acc2[4];

        if (doL1) {
#pragma unroll
            for (int nt = 0; nt < 8; ++nt)
                acc1[nt] = (f32x4){b1[nt], b1[nt], b1[nt], b1[nt]};
#pragma unroll
            for (int xt = 0; xt < 2; ++xt) {   // x hi, lo (same weight frag)
                const bf16x8 ax = *(const bf16x8*)&xs[l15][xt * 32 + quad * 8];
#pragma unroll
                for (int nt = 0; nt < 8; ++nt)
                    acc1[nt] = MFMA16(ax, wx1[nt], acc1[nt]);
            }
        }
        if (doL2) {
#pragma unroll
            for (int mt = 0; mt < 4; ++mt)
                acc2[mt] = (f32x4){b2[mt], b2[mt], b2[mt], b2[mt]};
        }
        // shared h1(t-1) A-frags feed both layers: kt 0-3 = hi, 4-7 = lo
#pragma unroll
        for (int kt = 0; kt < 8; ++kt) {
            const bf16x8 a = *(const bf16x8*)&h1s[l15][kt * 32 + quad * 8];
            if (doL1) {
#pragma unroll
                for (int nt = 0; nt < 8; ++nt)
                    acc1[nt] = MFMA16(a, wh1[nt][kt & 3], acc1[nt]);
            }
            if (doL2) {
#pragma unroll
                for (int mt = 0; mt < 4; ++mt)
                    acc2[mt] = MFMA16(a, wi2[mt][kt & 3], acc2[mt]);
            }
        }
        if (doL2) {
#pragma unroll
            for (int kt = 0; kt < 4; ++kt) {   // h2 hi (0-1), lo (2-3)
                const bf16x8 a = *(const bf16x8*)&h2s[l15][kt * 32 + quad * 8];
#pragma unroll
                for (int mt = 0; mt < 4; ++mt)
                    acc2[mt] = MFMA16(a, wh2[mt][kt & 1], acc2[mt]);
            }
        }
        if (quad == 0) {   // rows 0..3 are the valid rows
            if (doL1) {
#pragma unroll
                for (int nt = 0; nt < 8; ++nt)
#pragma unroll
                    for (int r = 0; r < ROWS; ++r)
                        g1r[r][wave * 128 + nt * 16 + l15] = acc1[nt][r];
            }
            if (doL2) {
#pragma unroll
                for (int mt = 0; mt < 4; ++mt)
#pragma unroll
                    for (int r = 0; r < ROWS; ++r)
                        g2r[r][wave * 64 + mt * 16 + l15] = acc2[mt][r];
            }
        }
        __syncthreads();   // B2: raw gates ready; h/x MFMA reads done

        // ---- epilogue phase: 2 L1 updates/thread; 1 L2 update/thread ----
        if (tt < T_SEQ) {
#pragma unroll
            for (int k = 0; k < 2; ++k) {
                const int idx = tid + 256 * k;
                const int row = idx >> 7, u = idx & 127;
                const float iv = fast_sigmoid(g1r[row][u]);
                const float fv = fast_sigmoid(g1r[row][128 + u]);
                const float gv = fast_tanh   (g1r[row][256 + u]);
                const float ov = fast_sigmoid(g1r[row][384 + u]);
                const float cn = fv * c1[k] + iv * gv;
                c1[k] = cn;
                const float h = ov * fast_tanh(cn);
                const ushort hi = f2bf(h);
                h1s[row][u]       = hi;
                h1s[row][128 + u] = f2bf(h - bf2f(hi));
            }
        }
        if (tt >= 1) {
            const float iv = fast_sigmoid(g2r[e2row][e2u]);
            const float fv = fast_sigmoid(g2r[e2row][64 + e2u]);
            const float gv = fast_tanh   (g2r[e2row][128 + e2u]);
            const float ov = fast_sigmoid(g2r[e2row][192 + e2u]);
            const float cn = fv * c2 + iv * gv;
            c2 = cn;
            const float h = ov * fast_tanh(cn);
            const ushort hi = f2bf(h);
            h2s[e2row][e2u]      = hi;
            h2s[e2row][64 + e2u] = f2bf(h - bf2f(hi));
            if (tt == T_SEQ)
                out[(size_t)(r0 + e2row) * E2 + e2u] = h;
        }
    }
}

extern "C" void kernel_launch(void* const* d_in, const int* in_sizes, int n_in,
                              void* d_out, int out_size, void* d_ws, size_t ws_size,
                              hipStream_t stream) {
    lstm_fused<<<128, 256, 0, stream>>>(
        (const float*)d_in[0], (const float*)d_in[1], (const float*)d_in[2],
        (const float*)d_in[3], (const float*)d_in[4], (const float*)d_in[5],
        (const float*)d_in[6], (const float*)d_in[7], (const float*)d_in[8],
        (float*)d_out);
}

// Round 3
// 1251.586 us; speedup vs baseline: 1.4734x; 1.4734x over previous
//
#include <hip/hip_runtime.h>

typedef __attribute__((ext_vector_type(8))) __bf16 bf16x8;
typedef __attribute__((ext_vector_type(4))) float f32x4;

#define MFMA16(a, b, c) __builtin_amdgcn_mfma_f32_16x16x32_bf16(a, b, c, 0, 0, 0)

#define T_SEQ 512
#define F_IN 32
#define H1 128
#define E2 64
#define ROWS 4          // batch rows per block

__device__ __forceinline__ float bf2f(ushort u) {
    union { uint i; float f; } v; v.i = ((uint)u) << 16; return v.f;
}
__device__ __forceinline__ ushort f2bf(float f) {
    union { float f; uint i; } v; v.f = f;
    uint r = v.i + 0x7fffu + ((v.i >> 16) & 1u);
    return (ushort)(r >> 16);
}
__device__ __forceinline__ float fast_sigmoid(float x) {
    float e = __expf(-x);
    return __builtin_amdgcn_rcpf(1.0f + e);
}
__device__ __forceinline__ float fast_tanh(float x) {
    float e = __expf(-2.0f * x);
    return 2.0f * __builtin_amdgcn_rcpf(1.0f + e) - 1.0f;
}
__device__ __forceinline__ bf16x8 load_w8(const float* p) {
    bf16x8 r;
#pragma unroll
    for (int j = 0; j < 8; ++j) r[j] = (__bf16)p[j];
    return r;
}

// Fused 2-layer LSTM, 128 blocks x 512 threads (8 waves), 4 batch rows/block.
//
// ROUND THEORY (arch-register cap, demand reduction): rounds 0-2 established
// that 8-wave blocks get 128 arch VGPRs/wave (+128 accum) and 4-wave blocks
// get 256 arch but double per-wave demand (r2: 2x time, 28MB spill). Demand
// above the arch cap goes to scratch, and the per-step scratch RELOADS are
// the ~3000 cyc/step hidden cost. Fix here: cut per-wave weight regs from
// 128 -> 96 by holding Wih1 and Whh2 in LDS as bf16 (only +8 ds_read_b128
// per wave-step, hidden under MFMA issue). Arch demand ~130 -> fits the
// 128-cap with cheap AGPR-copy absorption, scratch ~0.
// Also: ALL LDS strides padded to odd dword counts to kill the 2.3-2.9e7
// bank-conflict cycles (~350 cyc/step/CU).
__global__ __launch_bounds__(512, 1) void lstm_fused(
    const float* __restrict__ x,      // [512][512][32]
    const float* __restrict__ Wih1,   // [512][32]
    const float* __restrict__ Whh1,   // [512][128]
    const float* __restrict__ bih1,   // [512]
    const float* __restrict__ bhh1,   // [512]
    const float* __restrict__ Wih2,   // [256][128]
    const float* __restrict__ Whh2,   // [256][64]
    const float* __restrict__ bih2,   // [256]
    const float* __restrict__ bhh2,   // [256]
    float* __restrict__ out)          // [512][64] fp32
{
    __shared__ ushort xs [16][74];    // x(t): cols 0..31 hi, 32..63 lo (37 dw, odd)
    __shared__ ushort h1s[16][266];   // h1: cols 0..127 hi, 128..255 lo (133 dw)
    __shared__ ushort h2s[16][138];   // h2: cols 0..63 hi, 64..127 lo (69 dw)
    __shared__ float  g1r[ROWS][517]; // raw L1 gates (517 dw, odd)
    __shared__ float  g2r[ROWS][261]; // raw L2 gates
    __shared__ ushort w1L[512][34];   // Wih1 bf16 (17 dw stride, odd)
    __shared__ ushort w2L[256][66];   // Whh2 bf16 (33 dw stride, odd)

    const int tid  = threadIdx.x;
    const int wave = tid >> 6;
    const int lane = tid & 63;
    const int l15  = lane & 15;
    const int quad = lane >> 4;
    const int r0   = blockIdx.x * ROWS;
    const int w64  = wave * 64;       // this wave's L1 gate base
    const int w32  = wave * 32;       // this wave's L2 gate base

    // Register-resident weights (96 VGPRs/wave): the two big matrices.
    bf16x8 wh1[4][4];   // Whh1 rows w64+nt*16+l15, k-block kt      (64 regs)
    bf16x8 wi2[2][4];   // Wih2 rows w32+mt*16+l15, k-block kt      (32 regs)
    float  b1[4], b2[2];

#pragma unroll
    for (int nt = 0; nt < 4; ++nt) {
        const int n = w64 + nt * 16 + l15;
#pragma unroll
        for (int kt = 0; kt < 4; ++kt)
            wh1[nt][kt] = load_w8(Whh1 + n * H1 + kt * 32 + quad * 8);
        b1[nt] = bih1[n] + bhh1[n];
    }
#pragma unroll
    for (int mt = 0; mt < 2; ++mt) {
        const int n = w32 + mt * 16 + l15;
#pragma unroll
        for (int kt = 0; kt < 4; ++kt)
            wi2[mt][kt] = load_w8(Wih2 + n * H1 + kt * 32 + quad * 8);
        b2[mt] = bih2[n] + bhh2[n];
    }

    // LDS-resident weights, converted fp32->bf16 once (RNE, same as load_w8).
    for (int i = tid; i < 512 * F_IN; i += 512) w1L[i >> 5][i & 31] = f2bf(Wih1[i]);
    for (int i = tid; i < 256 * E2;  i += 512) w2L[i >> 6][i & 63] = f2bf(Whh2[i]);

    // zero h states (all 16 rows; rows >= ROWS stay zero forever)
    for (int i = tid; i < 16 * 266; i += 512) ((ushort*)h1s)[i] = 0;
    for (int i = tid; i < 16 * 138; i += 512) ((ushort*)h2s)[i] = 0;
    __syncthreads();

    // per-thread epilogue ownership + fp32 cell state
    const int e1row = tid >> 7, e1u = tid & 127;    // L1: all 512 threads
    const int e2row = tid >> 6, e2u = tid & 63;     // L2: tid < 256
    float c1 = 0.0f, c2 = 0.0f;

    // x prefetch: threads 0..127 own (row = tid>>5, col = tid&31)
    const int xrow = tid >> 5, xcol = tid & 31;
    const float* xptr = x + ((size_t)(r0 + (xrow & 3)) * T_SEQ) * F_IN + xcol;
    float xreg = (tid < 128) ? xptr[0] : 0.0f;

#pragma unroll 1
    for (int tt = 0; tt <= T_SEQ; ++tt) {
        // ---- stage x(tt), prefetch x(tt+1) ----
        if (tt < T_SEQ && tid < 128) {
            const ushort h = f2bf(xreg);
            xs[xrow][xcol]      = h;
            xs[xrow][32 + xcol] = f2bf(xreg - bf2f(h));
            if (tt + 1 < T_SEQ) xreg = xptr[(tt + 1) * F_IN];
        }
        __syncthreads();   // B1: xs(tt), h1(tt-1), h2(tt-2) ready

        // ---- GEMM phase: every wave does its L1 chunk AND its L2 chunk ----
        const bool doL1 = (tt < T_SEQ);
        const bool doL2 = (tt >= 1);
        f32x4 acc1[4], acc2[2];

        if (doL1) {
#pragma unroll
            for (int nt = 0; nt < 4; ++nt)
                acc1[nt] = (f32x4){b1[nt], b1[nt], b1[nt], b1[nt]};
            // Wih1 frags from LDS (reused for x hi and lo)
            bf16x8 wxf[4];
#pragma unroll
            for (int nt = 0; nt < 4; ++nt)
                wxf[nt] = *(const bf16x8*)&w1L[w64 + nt * 16 + l15][quad * 8];
#pragma unroll
            for (int xt = 0; xt < 2; ++xt) {   // x hi, lo (same weight frag)
                const bf16x8 ax = *(const bf16x8*)&xs[l15][xt * 32 + quad * 8];
#pragma unroll
                for (int nt = 0; nt < 4; ++nt)
                    acc1[nt] = MFMA16(ax, wxf[nt], acc1[nt]);
            }
        }
        if (doL2) {
#pragma unroll
            for (int mt = 0; mt < 2; ++mt)
                acc2[mt] = (f32x4){b2[mt], b2[mt], b2[mt], b2[mt]};
        }
        // shared h1(t-1) A-frags feed both layers: kt 0-3 = hi, 4-7 = lo
#pragma unroll
        for (int kt = 0; kt < 8; ++kt) {
            const bf16x8 a = *(const bf16x8*)&h1s[l15][kt * 32 + quad * 8];
            if (doL1) {
#pragma unroll
                for (int nt = 0; nt < 4; ++nt)
                    acc1[nt] = MFMA16(a, wh1[nt][kt & 3], acc1[nt]);
            }
            if (doL2) {
#pragma unroll
                for (int mt = 0; mt < 2; ++mt)
                    acc2[mt] = MFMA16(a, wi2[mt][kt & 3], acc2[mt]);
            }
        }
        if (doL2) {
            // Whh2 frags from LDS (reused for h2 hi and lo)
            bf16x8 wh2f[2][2];
#pragma unroll
            for (int mt = 0; mt < 2; ++mt)
#pragma unroll
                for (int kk = 0; kk < 2; ++kk)
                    wh2f[mt][kk] = *(const bf16x8*)&w2L[w32 + mt * 16 + l15][kk * 32 + quad * 8];
#pragma unroll
            for (int kt = 0; kt < 4; ++kt) {   // h2 hi (0-1), lo (2-3)
                const bf16x8 a = *(const bf16x8*)&h2s[l15][kt * 32 + quad * 8];
#pragma unroll
                for (int mt = 0; mt < 2; ++mt)
                    acc2[mt] = MFMA16(a, wh2f[mt][kt & 1], acc2[mt]);
            }
        }
        if (quad == 0) {   // rows 0..3 are the valid rows
            if (doL1) {
#pragma unroll
                for (int nt = 0; nt < 4; ++nt)
#pragma unroll
                    for (int r = 0; r < ROWS; ++r)
                        g1r[r][w64 + nt * 16 + l15] = acc1[nt][r];
            }
            if (doL2) {
#pragma unroll
                for (int mt = 0; mt < 2; ++mt)
#pragma unroll
                    for (int r = 0; r < ROWS; ++r)
                        g2r[r][w32 + mt * 16 + l15] = acc2[mt][r];
            }
        }
        __syncthreads();   // B2: raw gates ready; h/x MFMA reads done

        // ---- epilogue phase: 1 L1 update/thread; 1 L2 update for tid<256 ----
        if (tt < T_SEQ) {
            const float iv = fast_sigmoid(g1r[e1row][e1u]);
            const float fv = fast_sigmoid(g1r[e1row][128 + e1u]);
            const float gv = fast_tanh   (g1r[e1row][256 + e1u]);
            const float ov = fast_sigmoid(g1r[e1row][384 + e1u]);
            const float cn = fv * c1 + iv * gv;
            c1 = cn;
            const float h = ov * fast_tanh(cn);
            const ushort hi = f2bf(h);
            h1s[e1row][e1u]       = hi;
            h1s[e1row][128 + e1u] = f2bf(h - bf2f(hi));
        }
        if (tid < 256 && tt >= 1) {
            const float iv = fast_sigmoid(g2r[e2row][e2u]);
            const float fv = fast_sigmoid(g2r[e2row][64 + e2u]);
            const float gv = fast_tanh   (g2r[e2row][128 + e2u]);
            const float ov = fast_sigmoid(g2r[e2row][192 + e2u]);
            const float cn = fv * c2 + iv * gv;
            c2 = cn;
            const float h = ov * fast_tanh(cn);
            const ushort hi = f2bf(h);
            h2s[e2row][e2u]      = hi;
            h2s[e2row][64 + e2u] = f2bf(h - bf2f(hi));
            if (tt == T_SEQ)
                out[(size_t)(r0 + e2row) * E2 + e2u] = h;
        }
    }
}

extern "C" void kernel_launch(void* const* d_in, const int* in_sizes, int n_in,
                              void* d_out, int out_size, void* d_ws, size_t ws_size,
                              hipStream_t stream) {
    lstm_fused<<<128, 512, 0, stream>>>(
        (const float*)d_in[0], (const float*)d_in[1], (const float*)d_in[2],
        (const float*)d_in[3], (const float*)d_in[4], (const float*)d_in[5],
        (const float*)d_in[6], (const float*)d_in[7], (const float*)d_in[8],
        (float*)d_out);
}

// Round 4
// 732.873 us; speedup vs baseline: 2.5162x; 1.7078x over previous
//
#include <hip/hip_runtime.h>

typedef __attribute__((ext_vector_type(8))) __bf16 bf16x8;
typedef __attribute__((ext_vector_type(4))) float f32x4;

#define MFMA16(a, b, c) __builtin_amdgcn_mfma_f32_16x16x32_bf16(a, b, c, 0, 0, 0)

#define T_SEQ 512
#define F_IN 32
#define H1 128
#define E2 64
#define ROWS 4          // batch rows per block

__device__ __forceinline__ float bf2f(ushort u) {
    union { uint i; float f; } v; v.i = ((uint)u) << 16; return v.f;
}
__device__ __forceinline__ ushort f2bf(float f) {
    union { float f; uint i; } v; v.f = f;
    uint r = v.i + 0x7fffu + ((v.i >> 16) & 1u);
    return (ushort)(r >> 16);
}
__device__ __forceinline__ float fast_sigmoid(float x) {
    float e = __expf(-x);
    return __builtin_amdgcn_rcpf(1.0f + e);
}
__device__ __forceinline__ float fast_tanh(float x) {
    float e = __expf(-2.0f * x);
    return 2.0f * __builtin_amdgcn_rcpf(1.0f + e) - 1.0f;
}
__device__ __forceinline__ bf16x8 load_w8(const float* p) {
    bf16x8 r;
#pragma unroll
    for (int j = 0; j < 8; ++j) r[j] = (__bf16)p[j];
    return r;
}

// Fused 2-layer LSTM, 128 blocks x 512 threads, 4 batch rows per block.
//
// ROUND THEORY (stall kill): r0-r3 showed spill ~free, but ~2800 cyc/step of
// stall from 2-barrier lockstep + g1r/g2r LDS round-trip + 8x-redundant 1KB
// A-frag reads. This version:
//  - A-frag rows read as h1s[l15>>2] (4 lanes/addr -> LDS broadcast): C rows
//    quad*4+j all equal batch row 'quad', so acc[tau][0] (const idx!) holds
//    every gate this lane needs -> epilogue fully in-register on all 64
//    lanes, g1r/g2r deleted. Unique LDS bytes per A-read: 1KB -> 256B.
//  - ONE barrier/step: xs/h1s/h2s ping-pong double-buffered (p = tt&1);
//    GEMM reads [p], epilogue writes [p^1].
//  - wave tiling: L1 wave w owns 4 gates x units [32w,32w+32); L2 wave w
//    owns 4 gates x units [16w,16w+16)  -> per-wave MFMA counts unchanged.
//  - row strides = 272/144/80 ushorts (== 8 dwords mod 32): broadcast-read
//    starts 8r+4q -> max 2-way (free); epilogue writes conflict-free.
__global__ __launch_bounds__(512, 1) void lstm_fused(
    const float* __restrict__ x,      // [512][512][32]
    const float* __restrict__ Wih1,   // [512][32]
    const float* __restrict__ Whh1,   // [512][128]
    const float* __restrict__ bih1,   // [512]
    const float* __restrict__ bhh1,   // [512]
    const float* __restrict__ Wih2,   // [256][128]
    const float* __restrict__ Whh2,   // [256][64]
    const float* __restrict__ bih2,   // [256]
    const float* __restrict__ bhh2,   // [256]
    float* __restrict__ out)          // [512][64] fp32
{
    __shared__ __align__(16) ushort xs [2][ROWS][80];   // x: cols 0..31 hi, 32..63 lo
    __shared__ __align__(16) ushort h1s[2][ROWS][272];  // h1: 0..127 hi, 128..255 lo
    __shared__ __align__(16) ushort h2s[2][ROWS][144];  // h2: 0..63 hi, 64..127 lo

    const int tid  = threadIdx.x;
    const int wave = tid >> 6;
    const int lane = tid & 63;
    const int l15  = lane & 15;
    const int quad = lane >> 4;
    const int arow = l15 >> 2;        // broadcast A-row (batch row) for ds_reads
    const int r0   = blockIdx.x * ROWS;
    const bool isL1 = (wave < 4);
    const int w    = wave & 3;

    // Unified weight fragment file (disjoint per wave group):
    //  L1 (tau = g*2+uo, g=gate 0..3, uo=unit-16-group 0..1):
    //    wf[tau*4+kt] = Whh1 frag   (128 regs), wf[32+tau] = Wih1 frag (32)
    //  L2 (g = gate 0..3):
    //    wf[g*4+kt] = Wih2 frag (64), wf[16+g*2+kc] = Whh2 frag (32)
    bf16x8 wf[40];
    float  bias[8];

    if (isL1) {
#pragma unroll
        for (int g = 0; g < 4; ++g)
#pragma unroll
            for (int uo = 0; uo < 2; ++uo) {
                const int tau = g * 2 + uo;
                const int n = g * 128 + w * 32 + uo * 16 + l15;
#pragma unroll
                for (int kt = 0; kt < 4; ++kt)
                    wf[tau * 4 + kt] = load_w8(Whh1 + n * H1 + kt * 32 + quad * 8);
                wf[32 + tau] = load_w8(Wih1 + n * F_IN + quad * 8);
                bias[tau] = bih1[n] + bhh1[n];
            }
    } else {
#pragma unroll
        for (int g = 0; g < 4; ++g) {
            const int n = g * 64 + w * 16 + l15;
#pragma unroll
            for (int kt = 0; kt < 4; ++kt)
                wf[g * 4 + kt] = load_w8(Wih2 + n * H1 + kt * 32 + quad * 8);
#pragma unroll
            for (int kc = 0; kc < 2; ++kc)
                wf[16 + g * 2 + kc] = load_w8(Whh2 + n * E2 + kc * 32 + quad * 8);
            bias[g] = bih2[n] + bhh2[n];
        }
    }

    // zero both h-state buffers
    for (int i = tid; i < 2 * ROWS * 272; i += 512) ((ushort*)h1s)[i] = 0;
    for (int i = tid; i < 2 * ROWS * 144; i += 512) ((ushort*)h2s)[i] = 0;

    // cell states: lane (quad,l15) owns batch row 'quad'
    float cst[2] = {0.0f, 0.0f};      // L1: per uo; L2 uses cst[0]

    // x staging: threads 256..383 own (xrow = sid>>5 in 0..3, xcol = sid&31)
    const int sid  = tid - 256;
    const int xrow = (sid >> 5) & 3, xcol = sid & 31;
    const bool stager = (tid >= 256 && tid < 384);
    const float* xptr = x + ((size_t)(r0 + xrow) * T_SEQ) * F_IN + xcol;
    float xreg = 0.0f;
    if (stager) {
        const float x0 = xptr[0];
        const ushort h = f2bf(x0);
        xs[0][xrow][xcol]      = h;
        xs[0][xrow][32 + xcol] = f2bf(x0 - bf2f(h));
        xreg = xptr[F_IN];            // x(1)
    }
    __syncthreads();

    f32x4 acc[8];

#pragma unroll 1
    for (int tt = 0; tt <= T_SEQ; ++tt) {
        const int p  = tt & 1;
        const int pn = p ^ 1;

        if (isL1) {
            if (tt < T_SEQ) {
                // ---- L1 GEMM: 4 gates x 32 units, K = 64(x) + 256(h1) ----
#pragma unroll
                for (int tau = 0; tau < 8; ++tau)
                    acc[tau] = (f32x4){bias[tau], bias[tau], bias[tau], bias[tau]};
#pragma unroll
                for (int xt = 0; xt < 2; ++xt) {       // x hi, lo (same frag)
                    const bf16x8 ax = *(const bf16x8*)&xs[p][arow][xt * 32 + quad * 8];
#pragma unroll
                    for (int tau = 0; tau < 8; ++tau)
                        acc[tau] = MFMA16(ax, wf[32 + tau], acc[tau]);
                }
#pragma unroll
                for (int kt = 0; kt < 8; ++kt) {       // h1 hi (0-3), lo (4-7)
                    const bf16x8 a = *(const bf16x8*)&h1s[p][arow][kt * 32 + quad * 8];
#pragma unroll
                    for (int tau = 0; tau < 8; ++tau)
                        acc[tau] = MFMA16(a, wf[tau * 4 + (kt & 3)], acc[tau]);
                }
                // ---- L1 epilogue, in-register, all 64 lanes ----
                // lane (quad,l15): batch row 'quad', units w*32 + uo*16 + l15
#pragma unroll
                for (int uo = 0; uo < 2; ++uo) {
                    const int u = w * 32 + uo * 16 + l15;
                    const float iv = fast_sigmoid(acc[0 + uo][0]);
                    const float fv = fast_sigmoid(acc[2 + uo][0]);
                    const float gv = fast_tanh   (acc[4 + uo][0]);
                    const float ov = fast_sigmoid(acc[6 + uo][0]);
                    const float cn = fv * cst[uo] + iv * gv;
                    cst[uo] = cn;
                    const float h = ov * fast_tanh(cn);
                    const ushort hi = f2bf(h);
                    h1s[pn][quad][u]       = hi;
                    h1s[pn][quad][128 + u] = f2bf(h - bf2f(hi));
                }
            }
        } else {
            if (tt >= 1) {
                // ---- L2 GEMM: 4 gates x 16 units, K = 256(h1) + 128(h2) ----
#pragma unroll
                for (int g = 0; g < 4; ++g)
                    acc[g] = (f32x4){bias[g], bias[g], bias[g], bias[g]};
#pragma unroll
                for (int kt = 0; kt < 8; ++kt) {       // h1 hi+lo
                    const bf16x8 a = *(const bf16x8*)&h1s[p][arow][kt * 32 + quad * 8];
#pragma unroll
                    for (int g = 0; g < 4; ++g)
                        acc[g] = MFMA16(a, wf[g * 4 + (kt & 3)], acc[g]);
                }
#pragma unroll
                for (int kt = 0; kt < 4; ++kt) {       // h2 hi (0-1), lo (2-3)
                    const bf16x8 a = *(const bf16x8*)&h2s[p][arow][kt * 32 + quad * 8];
#pragma unroll
                    for (int g = 0; g < 4; ++g)
                        acc[g] = MFMA16(a, wf[16 + g * 2 + (kt & 1)], acc[g]);
                }
                // ---- L2 epilogue, in-register, all 64 lanes ----
                const int u = w * 16 + l15;
                const float iv = fast_sigmoid(acc[0][0]);
                const float fv = fast_sigmoid(acc[1][0]);
                const float gv = fast_tanh   (acc[2][0]);
                const float ov = fast_sigmoid(acc[3][0]);
                const float cn = fv * cst[0] + iv * gv;
                cst[0] = cn;
                const float h = ov * fast_tanh(cn);
                if (tt == T_SEQ) {
                    out[(size_t)(r0 + quad) * E2 + u] = h;
                } else {
                    const ushort hi = f2bf(h);
                    h2s[pn][quad][u]      = hi;
                    h2s[pn][quad][64 + u] = f2bf(h - bf2f(hi));
                }
            }
            // ---- x staging: write x(tt+1) into xs[pn], prefetch x(tt+2) ----
            if (stager && tt + 1 < T_SEQ) {
                const ushort h = f2bf(xreg);
                xs[pn][xrow][xcol]      = h;
                xs[pn][xrow][32 + xcol] = f2bf(xreg - bf2f(h));
                if (tt + 2 < T_SEQ) xreg = xptr[(size_t)(tt + 2) * F_IN];
            }
        }
        __syncthreads();   // single barrier: buf pn complete, buf p reads done
    }
}

extern "C" void kernel_launch(void* const* d_in, const int* in_sizes, int n_in,
                              void* d_out, int out_size, void* d_ws, size_t ws_size,
                              hipStream_t stream) {
    lstm_fused<<<128, 512, 0, stream>>>(
        (const float*)d_in[0], (const float*)d_in[1], (const float*)d_in[2],
        (const float*)d_in[3], (const float*)d_in[4], (const float*)d_in[5],
        (const float*)d_in[6], (const float*)d_in[7], (const float*)d_in[8],
        (float*)d_out);
}